// Round 7
// baseline (521.240 us; speedup 1.0000x reference)
//
#include <hip/hip_runtime.h>
#include <stdint.h>

#define T_TOK 4096
#define DIMD  1024
#define HIDN  2048
#define NEXP  8
#define RMAX  10240                 // routed: 8192 slots + 8*256 alignment pad
#define RROWS (RMAX + 2 * T_TOK)    // 18432 = 72 * 256 rows total

typedef float f32x4 __attribute__((ext_vector_type(4)));
typedef short s16x8 __attribute__((ext_vector_type(8)));

__device__ __forceinline__ uint16_t f2bf(float f) {
    uint32_t u = __builtin_bit_cast(uint32_t, f);
    u += 0x7fffu + ((u >> 16) & 1u);
    return (uint16_t)(u >> 16);
}
__device__ __forceinline__ float bf2f(uint32_t h) {
    return __builtin_bit_cast(float, h << 16);
}
__device__ __forceinline__ uint32_t pk2(float a, float b) {
    return (uint32_t)f2bf(a) | ((uint32_t)f2bf(b) << 16);
}
// swizzled LDS byte offset: 128B row pitch, XOR row bits into 16B-granule slot
__device__ __forceinline__ int swz(int r, int cbyte) {
    return r * 128 + (cbyte ^ ((r & 7) << 4));
}
// async global->LDS: 16B/lane, LDS dest = wave-uniform base + lane*16
__device__ __forceinline__ void gload16(const void* g, void* l) {
    __builtin_amdgcn_global_load_lds(
        (const __attribute__((address_space(1))) void*)g,
        (__attribute__((address_space(3))) void*)l, 16, 0, 0);
}
#define BAR()      asm volatile("s_barrier" ::: "memory")
#define WAIT_VM(n) asm volatile("s_waitcnt vmcnt(" #n ")" ::: "memory")
#define WAIT_LGKM0() asm volatile("s_waitcnt lgkmcnt(0)" ::: "memory")

// ---------------- small kernels ----------------

struct CvtArgs {
    const float* s[7];
    uint16_t*    d[7];
    int          nq[7];
    int          mode[7];   // 0 straight, 1 w1->interleaved, 2 w3->interleaved
};

// w13 interleave: dest N-row n' = (n>>4)*32 + (mode==2?16:0) + (n&15), so that
// within each 32-row granule rows 0-15 are w1 and 16-31 are w3 of the same
// 16 hidden channels -> silu pair lands in adjacent MFMA col-fragments.
__global__ void cvt_all_kernel(CvtArgs a) {
    int base = blockIdx.x * blockDim.x + threadIdx.x;
    int stride = gridDim.x * blockDim.x;
    #pragma unroll
    for (int seg = 0; seg < 7; ++seg) {
        const float4* sp = (const float4*)a.s[seg];
        uint2* dp = (uint2*)a.d[seg];
        int n = a.nq[seg];
        int mode = a.mode[seg];
        for (int i = base; i < n; i += stride) {
            float4 v = sp[i];
            uint2 o; o.x = pk2(v.x, v.y); o.y = pk2(v.z, v.w);
            int di = i;
            if (mode) {
                int e = i >> 19;            // quads per src expert: 2048*256 = 2^19
                int rem = i & 524287;
                int nr = rem >> 8;          // source N row
                int kq = rem & 255;
                int np = ((nr >> 4) << 5) + ((mode == 2) ? 16 : 0) + (nr & 15);
                di = (e << 20) + (np << 8) + kq;   // quads per dst expert: 4096*256 = 2^20
            }
            dp[di] = o;
        }
    }
}

// Router: 128 blocks x 256 thr; rw staged in LDS; 1 wave = 8 tokens.
__global__ __launch_bounds__(256)
void router_kernel(const float* __restrict__ x, const float* __restrict__ rw,
                   const float* __restrict__ bias,
                   int* __restrict__ sel, float* __restrict__ wgt,
                   int* __restrict__ cnt) {
    __shared__ float rws[NEXP * DIMD];
    int tid = threadIdx.x;
    for (int i = tid; i < NEXP * DIMD / 4; i += 256)
        ((float4*)rws)[i] = ((const float4*)rw)[i];
    __syncthreads();

    int wid = tid >> 6, lane = tid & 63;
    float b[NEXP];
    #pragma unroll
    for (int e = 0; e < NEXP; ++e) b[e] = bias[e];

    int t0 = (blockIdx.x * 4 + wid) * 8;
    for (int j = 0; j < 8; ++j) {
        int t = t0 + j;
        const float4* xr = (const float4*)(x + (size_t)t * DIMD);
        float p[NEXP] = {};
        #pragma unroll
        for (int c = 0; c < 4; ++c) {
            float4 xv = xr[c * 64 + lane];
            #pragma unroll
            for (int e = 0; e < NEXP; ++e) {
                float4 wv = *(const float4*)(rws + e * DIMD + c * 256 + lane * 4);
                p[e] += xv.x * wv.x + xv.y * wv.y + xv.z * wv.z + xv.w * wv.w;
            }
        }
        #pragma unroll
        for (int off = 32; off >= 1; off >>= 1) {
            #pragma unroll
            for (int e = 0; e < NEXP; ++e) p[e] += __shfl_xor(p[e], off, 64);
        }
        if (lane == 0) {
            #pragma unroll
            for (int e = 0; e < NEXP; ++e) p[e] += b[e];
            float l0 = -1e30f; int i0 = 0;
            #pragma unroll
            for (int e = 0; e < NEXP; ++e) { if (p[e] > l0) { l0 = p[e]; i0 = e; } }
            float l1 = -1e30f; int i1 = 0;
            #pragma unroll
            for (int e = 0; e < NEXP; ++e) { if (e == i0) continue; if (p[e] > l1) { l1 = p[e]; i1 = e; } }
            float e1 = expf(l1 - l0);      // l0 >= l1 -> e1 <= 1
            float d = 1.f + e1;
            sel[t * 2] = i0; sel[t * 2 + 1] = i1;
            wgt[t * 2] = 1.f / d; wgt[t * 2 + 1] = e1 / d;
            atomicAdd(&cnt[i0], 1);
            atomicAdd(&cnt[i1], 1);
        }
    }
}

__global__ void offs_kernel(const int* __restrict__ cnt, int* __restrict__ offs) {
    if (threadIdx.x == 0 && blockIdx.x == 0) {
        int o = 0;
        for (int e = 0; e < NEXP; ++e) { offs[e] = o; o += (cnt[e] + 255) & ~255; }  // 256-align
        offs[NEXP] = o;
    }
}

// slot -> row, row -> token (tok); also fills tok for the shared segments.
__global__ void assign_kernel(const int* __restrict__ sel, const int* __restrict__ offs,
                              int* __restrict__ fill, int* __restrict__ row_of,
                              int* __restrict__ tok) {
    int i = blockIdx.x * blockDim.x + threadIdx.x;
    if (i < 2 * T_TOK) {
        int e = sel[i];
        int r = offs[e] + atomicAdd(&fill[e], 1);
        row_of[i] = r;
        tok[r] = i >> 1;
    } else if (i < 4 * T_TOK) {
        int j = i - 2 * T_TOK;                       // 0..8191: shared rows
        tok[offs[NEXP] + j] = j & (T_TOK - 1);
    }
}

// out[t] = w0*H2[r0] + w1*H2[r1] + H2[s0] + H2[s1]  (pure write)
__global__ void combine_kernel(const uint16_t* __restrict__ H2, const int* __restrict__ row_of,
                               const float* __restrict__ wgt, const int* __restrict__ offs,
                               float* __restrict__ out) {
    int t = blockIdx.x;
    int c = threadIdx.x * 8;   // 128 threads * 8 cols
    int r0 = row_of[t * 2], r1 = row_of[t * 2 + 1];
    int s0 = offs[NEXP] + t, s1 = s0 + T_TOK;
    float w0 = wgt[t * 2], w1 = wgt[t * 2 + 1];
    uint4 a = *(const uint4*)(H2 + (size_t)r0 * DIMD + c);
    uint4 b = *(const uint4*)(H2 + (size_t)r1 * DIMD + c);
    uint4 u = *(const uint4*)(H2 + (size_t)s0 * DIMD + c);
    uint4 v = *(const uint4*)(H2 + (size_t)s1 * DIMD + c);
    float4 o0, o1;
    o0.x = w0 * bf2f(a.x & 0xffffu) + w1 * bf2f(b.x & 0xffffu) + bf2f(u.x & 0xffffu) + bf2f(v.x & 0xffffu);
    o0.y = w0 * bf2f(a.x >> 16)     + w1 * bf2f(b.x >> 16)     + bf2f(u.x >> 16)     + bf2f(v.x >> 16);
    o0.z = w0 * bf2f(a.y & 0xffffu) + w1 * bf2f(b.y & 0xffffu) + bf2f(u.y & 0xffffu) + bf2f(v.y & 0xffffu);
    o0.w = w0 * bf2f(a.y >> 16)     + w1 * bf2f(b.y >> 16)     + bf2f(u.y >> 16)     + bf2f(v.y >> 16);
    o1.x = w0 * bf2f(a.z & 0xffffu) + w1 * bf2f(b.z & 0xffffu) + bf2f(u.z & 0xffffu) + bf2f(v.z & 0xffffu);
    o1.y = w0 * bf2f(a.z >> 16)     + w1 * bf2f(b.z >> 16)     + bf2f(u.z >> 16)     + bf2f(v.z >> 16);
    o1.z = w0 * bf2f(a.w & 0xffffu) + w1 * bf2f(b.w & 0xffffu) + bf2f(u.w & 0xffffu) + bf2f(v.w & 0xffffu);
    o1.w = w0 * bf2f(a.w >> 16)     + w1 * bf2f(b.w >> 16)     + bf2f(u.w >> 16)     + bf2f(v.w >> 16);
    float* o = out + (size_t)t * DIMD + c;
    *(float4*)o = o0;
    *(float4*)(o + 4) = o1;
}

// ---------------- 8-phase-style GEMM, 256x128 tile, BK=64 ----------------
// 512 thr = 8 waves (4M x 2N), wave output 64x64 (acc 4x4 frags).
// 3 LDS buffers (A 32K + B 16K each = 144 KiB): during tile t's phase 0 we
// stage tile t+2; at tile t's end, counted s_waitcnt vmcnt(6) waits for t+1
// only (t+2's 6 loads stay in flight across the barrier). Raw s_barrier (no
// compiler vmcnt(0) drain). setprio(1) around each 16-MFMA cluster.
// Buffer safety: stage(t+2) overwrites buf[(t-1)%3], whose last reads were
// lgkm-waited before tile t-1's final barrier.
template<int IND, int SILU>
__global__ __launch_bounds__(512, 2)
void gemm8p_kernel(const uint16_t* __restrict__ A, const int* __restrict__ tok,
                   const uint16_t* __restrict__ W, uint16_t* __restrict__ Cout,
                   const int* __restrict__ offs, int N, int K) {
    __shared__ __align__(16) char lds[3 * 49152];

    int row0 = blockIdx.y * 256;
    int rsh = row0 - offs[NEXP];
    int e;
    if (rsh >= 0) {
        if (rsh >= 2 * T_TOK) return;
        e = NEXP + (rsh >> 12);
    } else {
        e = 0;
        while (row0 >= offs[e + 1]) ++e;
    }
    const uint16_t* wp = W + (size_t)e * ((size_t)N * K);
    int col0 = blockIdx.x * 128;

    int tid = threadIdx.x, lane = tid & 63;
    int wid = tid >> 6, wm = wid >> 1, wn = wid & 1;

    // staging source offsets (elements); inverse-swizzled so reads use swz()
    uint32_t asrc[4];
    #pragma unroll
    for (int p = 0; p < 4; ++p) {
        int s = p * 512 + tid;
        int r = s >> 3;
        int cb = ((s & 7) << 4) ^ ((r & 7) << 4);
        int grow = IND ? tok[row0 + r] : (row0 + r);
        asrc[p] = (uint32_t)grow * (uint32_t)K + (cb >> 1);
    }
    uint32_t bsrc[2];
    #pragma unroll
    for (int p = 0; p < 2; ++p) {
        int s = p * 512 + tid;
        int r = s >> 3;
        int cb = ((s & 7) << 4) ^ ((r & 7) << 4);
        bsrc[p] = (uint32_t)(col0 + r) * (uint32_t)K + (cb >> 1);
    }
    int ldsA = wid * 1024;           // wave-uniform LDS dest base offsets
    int ldsB = 32768 + wid * 1024;

    int nt = K / 64;
    f32x4 acc[4][4] = {};

    auto STAGE = [&](int t) {
        char* buf = lds + (t % 3) * 49152;
        int kt = t * 64;
        #pragma unroll
        for (int p = 0; p < 4; ++p)
            gload16(A + asrc[p] + kt, buf + p * 8192 + ldsA);
        #pragma unroll
        for (int p = 0; p < 2; ++p)
            gload16(wp + bsrc[p] + kt, buf + 32768 + p * 8192 + (ldsB - 32768));
    };

    int arow = wm * 64 + (lane & 15);
    int brow = wn * 64 + (lane & 15);
    int khi = (lane >> 4) << 4;      // 0,16,32,48 byte slot within k

    STAGE(0);
    STAGE(1);
    WAIT_VM(6);                      // tile 0 landed; tile 1's 6 still flying
    BAR();

    for (int t = 0; t < nt; ++t) {
        char* As = lds + (t % 3) * 49152;
        char* Bs = As + 32768;

        // ---- phase 0: a-frags(8) + b-frags j=0,1 (4); prefetch tile t+2
        s16x8 av[2][4], bv[2][2];
        #pragma unroll
        for (int ks = 0; ks < 2; ++ks)
            #pragma unroll
            for (int i = 0; i < 4; ++i)
                av[ks][i] = *(const s16x8*)(As + swz(arow + i * 16, ks * 64 + khi));
        #pragma unroll
        for (int ks = 0; ks < 2; ++ks)
            #pragma unroll
            for (int j = 0; j < 2; ++j)
                bv[ks][j] = *(const s16x8*)(Bs + swz(brow + j * 16, ks * 64 + khi));
        if (t + 2 < nt) STAGE(t + 2);
        BAR();
        WAIT_LGKM0();
        __builtin_amdgcn_s_setprio(1);
        #pragma unroll
        for (int ks = 0; ks < 2; ++ks)
            #pragma unroll
            for (int j = 0; j < 2; ++j)
                #pragma unroll
                for (int i = 0; i < 4; ++i)
                    acc[i][j] = __builtin_amdgcn_mfma_f32_16x16x32_bf16(av[ks][i], bv[ks][j], acc[i][j], 0, 0, 0);
        __builtin_amdgcn_s_setprio(0);
        BAR();

        // ---- phase 1: b-frags j=2,3; a-frags reused from registers
        s16x8 bv2[2][2];
        #pragma unroll
        for (int ks = 0; ks < 2; ++ks)
            #pragma unroll
            for (int j = 0; j < 2; ++j)
                bv2[ks][j] = *(const s16x8*)(Bs + swz(brow + (j + 2) * 16, ks * 64 + khi));
        BAR();
        WAIT_LGKM0();
        __builtin_amdgcn_s_setprio(1);
        #pragma unroll
        for (int ks = 0; ks < 2; ++ks)
            #pragma unroll
            for (int j = 0; j < 2; ++j)
                #pragma unroll
                for (int i = 0; i < 4; ++i)
                    acc[i][j + 2] = __builtin_amdgcn_mfma_f32_16x16x32_bf16(av[ks][i], bv2[ks][j], acc[i][j + 2], 0, 0, 0);
        __builtin_amdgcn_s_setprio(0);
        // tile boundary: wait for tile t+1 (counted; t+2's loads keep flying)
        if (t + 2 < nt) {
            WAIT_VM(6);
        } else if (t + 1 < nt) {
            WAIT_VM(0);
        }
        BAR();
    }

    // ---- epilogue
    #pragma unroll
    for (int i = 0; i < 4; ++i) {
        int row = row0 + wm * 64 + i * 16 + ((lane >> 4) << 2);
        if (SILU) {
            // cols interleaved: j=2m is w1-frag, j=2m+1 is w3-frag of the
            // same 16 hidden channels; h-col = (col0+wn*64)/2 + m*16 + lane&15
            #pragma unroll
            for (int m = 0; m < 2; ++m) {
                int hc = ((col0 + wn * 64) >> 1) + m * 16 + (lane & 15);
                #pragma unroll
                for (int rg = 0; rg < 4; ++rg) {
                    float a1 = acc[i][2 * m][rg];
                    float a3 = acc[i][2 * m + 1][rg];
                    float hv = (a1 / (1.f + __expf(-a1))) * a3;
                    Cout[(size_t)(row + rg) * HIDN + hc] = f2bf(hv);
                }
            }
        } else {
            #pragma unroll
            for (int j = 0; j < 4; ++j) {
                int c = col0 + wn * 64 + j * 16 + (lane & 15);
                #pragma unroll
                for (int rg = 0; rg < 4; ++rg)
                    Cout[(size_t)(row + rg) * N + c] = f2bf(acc[i][j][rg]);
            }
        }
    }
}

// ---------------- launch ----------------

extern "C" void kernel_launch(void* const* d_in, const int* in_sizes, int n_in,
                              void* d_out, int out_size, void* d_ws, size_t ws_size,
                              hipStream_t stream) {
    const float* x   = (const float*)d_in[0];
    const float* rw  = (const float*)d_in[1];
    const float* eb  = (const float*)d_in[2];
    const float* w1  = (const float*)d_in[3];
    const float* w3  = (const float*)d_in[4];
    const float* w2  = (const float*)d_in[5];
    const float* sw1 = (const float*)d_in[6];
    const float* sw3 = (const float*)d_in[7];
    const float* sw2 = (const float*)d_in[8];
    float* out = (float*)d_out;

    const size_t EW = (size_t)NEXP * HIDN * DIMD;   // elements per routed weight set
    const size_t SW = (size_t)2 * HIDN * DIMD;      // elements per shared weight set

    char* ws = (char*)d_ws;
    size_t off = 0;
    auto alloc = [&](size_t b) { char* p = ws + off; off = (off + b + 255) & ~(size_t)255; return p; };
    uint16_t* xb    = (uint16_t*)alloc((size_t)T_TOK * DIMD * 2);    // x in bf16
    uint16_t* Hg    = (uint16_t*)alloc((size_t)RROWS * HIDN * 2);    // hidden, unified rows
    uint16_t* H2    = (uint16_t*)alloc((size_t)RROWS * DIMD * 2);    // FFN outputs
    uint16_t* w13   = (uint16_t*)alloc((size_t)10 * 4096 * 1024 * 2); // w1/w3 interleaved, 10 experts
    uint16_t* w2all = (uint16_t*)alloc((EW + SW) * 2);
    int*   sel    = (int*)  alloc(T_TOK * 2 * 4);
    float* wgt    = (float*)alloc(T_TOK * 2 * 4);
    int*   row_of = (int*)  alloc(T_TOK * 2 * 4);
    int*   tok    = (int*)  alloc(RROWS * 4);
    int*   cnt    = (int*)  alloc(64);
    int*   fill   = (int*)  alloc(64);
    int*   offs   = (int*)  alloc(64);

    hipMemsetAsync(cnt, 0, 64, stream);
    hipMemsetAsync(fill, 0, 64, stream);
    hipMemsetAsync(tok, 0, RROWS * 4, stream);   // pad rows -> token 0 (harmless)

    // all f32->bf16 conversions in one HBM-bound pass; w1/w3 interleave into w13
    CvtArgs ca;
    ca.s[0] = w1;  ca.d[0] = w13;                          ca.nq[0] = (int)(EW / 4); ca.mode[0] = 1;
    ca.s[1] = sw1; ca.d[1] = w13 + (size_t)8 * 4096 * 1024; ca.nq[1] = (int)(SW / 4); ca.mode[1] = 1;
    ca.s[2] = w3;  ca.d[2] = w13;                          ca.nq[2] = (int)(EW / 4); ca.mode[2] = 2;
    ca.s[3] = sw3; ca.d[3] = w13 + (size_t)8 * 4096 * 1024; ca.nq[3] = (int)(SW / 4); ca.mode[3] = 2;
    ca.s[4] = w2;  ca.d[4] = w2all;                        ca.nq[4] = (int)(EW / 4); ca.mode[4] = 0;
    ca.s[5] = sw2; ca.d[5] = w2all + EW;                   ca.nq[5] = (int)(SW / 4); ca.mode[5] = 0;
    ca.s[6] = x;   ca.d[6] = xb;                           ca.nq[6] = T_TOK * DIMD / 4; ca.mode[6] = 0;
    cvt_all_kernel<<<2048, 256, 0, stream>>>(ca);

    router_kernel<<<128, 256, 0, stream>>>(x, rw, eb, sel, wgt, cnt);
    offs_kernel<<<1, 1, 0, stream>>>(cnt, offs);
    assign_kernel<<<64, 256, 0, stream>>>(sel, offs, fill, row_of, tok);

    // unified expert FFN over all rows (routed segments + 2 shared segments)
    gemm8p_kernel<1, 1><<<dim3(32, RROWS / 256), 512, 0, stream>>>(xb, tok, w13, Hg, offs, 4096, 1024);
    gemm8p_kernel<0, 0><<<dim3(8, RROWS / 256), 512, 0, stream>>>(Hg, nullptr, w2all, H2, offs, 1024, 2048);

    combine_kernel<<<T_TOK, 128, 0, stream>>>(H2, row_of, wgt, offs, out);
}

// Round 8
// 492.353 us; speedup vs baseline: 1.0587x; 1.0587x over previous
//
#include <hip/hip_runtime.h>
#include <stdint.h>

#define T_TOK 4096
#define DIMD  1024
#define HIDN  2048
#define NEXP  8
#define RMAX  10240                 // routed: 8192 slots + 8*256 alignment pad
#define RROWS (RMAX + 2 * T_TOK)    // 18432 = 72*256 = 144*128 rows total

typedef float f32x4 __attribute__((ext_vector_type(4)));
typedef short s16x8 __attribute__((ext_vector_type(8)));

__device__ __forceinline__ uint16_t f2bf(float f) {
    uint32_t u = __builtin_bit_cast(uint32_t, f);
    u += 0x7fffu + ((u >> 16) & 1u);
    return (uint16_t)(u >> 16);
}
__device__ __forceinline__ float bf2f(uint32_t h) {
    return __builtin_bit_cast(float, h << 16);
}
__device__ __forceinline__ uint32_t pk2(float a, float b) {
    return (uint32_t)f2bf(a) | ((uint32_t)f2bf(b) << 16);
}
// m97-style swizzle (gemm2): 128B row pitch, XOR row bits into 16B granule
__device__ __forceinline__ int swz(int r, int cbyte) {
    return r * 128 + (cbyte ^ ((r & 7) << 4));
}
__device__ __forceinline__ void gload16(const void* g, void* l) {
    __builtin_amdgcn_global_load_lds(
        (const __attribute__((address_space(1))) void*)g,
        (__attribute__((address_space(3))) void*)l, 16, 0, 0);
}
#define BAR()        asm volatile("s_barrier" ::: "memory")
#define WAIT_VM4()   asm volatile("s_waitcnt vmcnt(4)" ::: "memory")
#define WAIT_VM0()   asm volatile("s_waitcnt vmcnt(0)" ::: "memory")
#define WAIT_LGKM0() asm volatile("s_waitcnt lgkmcnt(0)" ::: "memory")

// Stage a 128x64 bf16 tile (16KB) into LDS, m97 layout (gemm2 only).
__device__ __forceinline__ void stage128x64(const uint16_t* gbase, int ldk,
                                            char* lds, int wv, int lane) {
    #pragma unroll
    for (int i = 0; i < 4; ++i) {
        int s = (wv * 4 + i) * 64 + lane;
        int row = s >> 3;
        int cb = ((s & 7) << 4) ^ ((row & 7) << 4);
        gload16(gbase + (size_t)row * ldk + (cb >> 1), lds + ((wv * 4 + i) << 10));
    }
}

// ---------------- small kernels ----------------

struct CvtArgs {
    const float* s[7];
    uint16_t*    d[7];
    int          nq[7];
    int          mode[7];   // 0 straight, 1 w1->interleaved, 2 w3->interleaved
};

// w13 interleave: dest N-row n' = (n>>4)*32 + (mode==2?16:0) + (n&15): within each
// 32-row granule rows 0-15 are w1, 16-31 are w3 of the same 16 hidden channels.
__global__ void cvt_all_kernel(CvtArgs a) {
    int base = blockIdx.x * blockDim.x + threadIdx.x;
    int stride = gridDim.x * blockDim.x;
    #pragma unroll
    for (int seg = 0; seg < 7; ++seg) {
        const float4* sp = (const float4*)a.s[seg];
        uint2* dp = (uint2*)a.d[seg];
        int n = a.nq[seg];
        int mode = a.mode[seg];
        for (int i = base; i < n; i += stride) {
            float4 v = sp[i];
            uint2 o; o.x = pk2(v.x, v.y); o.y = pk2(v.z, v.w);
            int di = i;
            if (mode) {
                int e = i >> 19;            // quads per src expert: 2048*256 = 2^19
                int rem = i & 524287;
                int nr = rem >> 8;          // source N row
                int kq = rem & 255;
                int np = ((nr >> 4) << 5) + ((mode == 2) ? 16 : 0) + (nr & 15);
                di = (e << 20) + (np << 8) + kq;
            }
            dp[di] = o;
        }
    }
}

// Router: 128 blocks x 256 thr; rw staged in LDS; 1 wave = 8 tokens.
__global__ __launch_bounds__(256)
void router_kernel(const float* __restrict__ x, const float* __restrict__ rw,
                   const float* __restrict__ bias,
                   int* __restrict__ sel, float* __restrict__ wgt,
                   int* __restrict__ cnt) {
    __shared__ float rws[NEXP * DIMD];
    int tid = threadIdx.x;
    for (int i = tid; i < NEXP * DIMD / 4; i += 256)
        ((float4*)rws)[i] = ((const float4*)rw)[i];
    __syncthreads();

    int wid = tid >> 6, lane = tid & 63;
    float b[NEXP];
    #pragma unroll
    for (int e = 0; e < NEXP; ++e) b[e] = bias[e];

    int t0 = (blockIdx.x * 4 + wid) * 8;
    for (int j = 0; j < 8; ++j) {
        int t = t0 + j;
        const float4* xr = (const float4*)(x + (size_t)t * DIMD);
        float p[NEXP] = {};
        #pragma unroll
        for (int c = 0; c < 4; ++c) {
            float4 xv = xr[c * 64 + lane];
            #pragma unroll
            for (int e = 0; e < NEXP; ++e) {
                float4 wv = *(const float4*)(rws + e * DIMD + c * 256 + lane * 4);
                p[e] += xv.x * wv.x + xv.y * wv.y + xv.z * wv.z + xv.w * wv.w;
            }
        }
        #pragma unroll
        for (int off = 32; off >= 1; off >>= 1) {
            #pragma unroll
            for (int e = 0; e < NEXP; ++e) p[e] += __shfl_xor(p[e], off, 64);
        }
        if (lane == 0) {
            #pragma unroll
            for (int e = 0; e < NEXP; ++e) p[e] += b[e];
            float l0 = -1e30f; int i0 = 0;
            #pragma unroll
            for (int e = 0; e < NEXP; ++e) { if (p[e] > l0) { l0 = p[e]; i0 = e; } }
            float l1 = -1e30f; int i1 = 0;
            #pragma unroll
            for (int e = 0; e < NEXP; ++e) { if (e == i0) continue; if (p[e] > l1) { l1 = p[e]; i1 = e; } }
            float e1 = expf(l1 - l0);      // l0 >= l1 -> e1 <= 1
            float d = 1.f + e1;
            sel[t * 2] = i0; sel[t * 2 + 1] = i1;
            wgt[t * 2] = 1.f / d; wgt[t * 2 + 1] = e1 / d;
            atomicAdd(&cnt[i0], 1);
            atomicAdd(&cnt[i1], 1);
        }
    }
}

__global__ void offs_kernel(const int* __restrict__ cnt, int* __restrict__ offs) {
    if (threadIdx.x == 0 && blockIdx.x == 0) {
        int o = 0;
        for (int e = 0; e < NEXP; ++e) { offs[e] = o; o += (cnt[e] + 255) & ~255; }  // 256-align
        offs[NEXP] = o;
    }
}

__global__ void assign_kernel(const int* __restrict__ sel, const int* __restrict__ offs,
                              int* __restrict__ fill, int* __restrict__ row_of,
                              int* __restrict__ tok) {
    int i = blockIdx.x * blockDim.x + threadIdx.x;
    if (i < 2 * T_TOK) {
        int e = sel[i];
        int r = offs[e] + atomicAdd(&fill[e], 1);
        row_of[i] = r;
        tok[r] = i >> 1;
    } else if (i < 4 * T_TOK) {
        int j = i - 2 * T_TOK;                       // 0..8191: shared rows
        tok[offs[NEXP] + j] = j & (T_TOK - 1);
    }
}

// out[t] = w0*H2[r0] + w1*H2[r1] + H2[s0] + H2[s1]  (pure write)
__global__ void combine_kernel(const uint16_t* __restrict__ H2, const int* __restrict__ row_of,
                               const float* __restrict__ wgt, const int* __restrict__ offs,
                               float* __restrict__ out) {
    int t = blockIdx.x;
    int c = threadIdx.x * 8;   // 128 threads * 8 cols
    int r0 = row_of[t * 2], r1 = row_of[t * 2 + 1];
    int s0 = offs[NEXP] + t, s1 = s0 + T_TOK;
    float w0 = wgt[t * 2], w1 = wgt[t * 2 + 1];
    uint4 a = *(const uint4*)(H2 + (size_t)r0 * DIMD + c);
    uint4 b = *(const uint4*)(H2 + (size_t)r1 * DIMD + c);
    uint4 u = *(const uint4*)(H2 + (size_t)s0 * DIMD + c);
    uint4 v = *(const uint4*)(H2 + (size_t)s1 * DIMD + c);
    float4 o0, o1;
    o0.x = w0 * bf2f(a.x & 0xffffu) + w1 * bf2f(b.x & 0xffffu) + bf2f(u.x & 0xffffu) + bf2f(v.x & 0xffffu);
    o0.y = w0 * bf2f(a.x >> 16)     + w1 * bf2f(b.x >> 16)     + bf2f(u.x >> 16)     + bf2f(v.x >> 16);
    o0.z = w0 * bf2f(a.y & 0xffffu) + w1 * bf2f(b.y & 0xffffu) + bf2f(u.y & 0xffffu) + bf2f(v.y & 0xffffu);
    o0.w = w0 * bf2f(a.y >> 16)     + w1 * bf2f(b.y >> 16)     + bf2f(u.y >> 16)     + bf2f(v.y >> 16);
    o1.x = w0 * bf2f(a.z & 0xffffu) + w1 * bf2f(b.z & 0xffffu) + bf2f(u.z & 0xffffu) + bf2f(v.z & 0xffffu);
    o1.y = w0 * bf2f(a.z >> 16)     + w1 * bf2f(b.z >> 16)     + bf2f(u.z >> 16)     + bf2f(v.z >> 16);
    o1.z = w0 * bf2f(a.w & 0xffffu) + w1 * bf2f(b.w & 0xffffu) + bf2f(u.w & 0xffffu) + bf2f(v.w & 0xffffu);
    o1.w = w0 * bf2f(a.w >> 16)     + w1 * bf2f(b.w >> 16)     + bf2f(u.w >> 16)     + bf2f(v.w >> 16);
    float* o = out + (size_t)t * DIMD + c;
    *(float4*)o = o0;
    *(float4*)(o + 4) = o1;
}

// ------------- gemm13: 256x256 tile, BK=64, 4-phase counted-vmcnt pipeline -------------
// 512 thr = 8 waves (2M x 4N); per-wave C = 128x64 = acc[8][4] frags.
// LDS: 2 bufs x (A 32K + B 32K); each 32K block = [ks][256 rows][64B], slot-swizzled
// (s ^= row&3). Half-tile = one (arr,ks) 16KB unit = 2 gload16/thread.
// Per K-tile, 4 phases; each: {ds_reads, 1 half-tile stage, BAR, lgkm0, 16 MFMA, BAR}.
// Ledger (loads/thread): entry outstanding = 4 (= ks1(t)). ph1 +2 (Aks0 t+1),
// ph2 +2 (Bks0 t+1) -> vmcnt(4) lands ks1(t) before ph3 reads. ph3 +2 (Aks1 t+1),
// ph4 +2 (Bks1 t+1) -> vmcnt(4) lands ks0(t+1) before next tile. Never drains.
__global__ __launch_bounds__(512, 2)
void gemm13_8p(const uint16_t* __restrict__ A, const int* __restrict__ tok,
               const uint16_t* __restrict__ W, uint16_t* __restrict__ H,
               const int* __restrict__ offs) {
    constexpr int K = DIMD;       // 1024
    constexpr int NT = K / 64;    // 16 K-tiles
    __shared__ __align__(16) char lds[131072];

    int row0 = blockIdx.y * 256;
    int rsh = row0 - offs[NEXP];
    int e;
    if (rsh >= 0) {
        if (rsh >= 2 * T_TOK) return;
        e = NEXP + (rsh >> 12);
    } else {
        e = 0;
        while (row0 >= offs[e + 1]) ++e;
    }
    const uint16_t* wp = W + (size_t)e * (4096ull * 1024ull);
    int col0 = blockIdx.x * 256;

    int tid = threadIdx.x, lane = tid & 63, wid = tid >> 6;
    int wm = wid >> 2, wn = wid & 3;

    // staging constants: issue i covers rows i*128 + (tid>>2), granule tid&3,
    // source slot = (lane&3) ^ ((lane>>2)&3)  (inverse of read-side swizzle)
    int sslot = (lane & 3) ^ ((lane >> 2) & 3);
    uint32_t aoff[2], boff[2];
    #pragma unroll
    for (int i = 0; i < 2; ++i) {
        int r = i * 128 + (tid >> 2);
        int garow = tok[row0 + r];
        aoff[i] = (uint32_t)garow * K + sslot * 8;
        boff[i] = (uint32_t)(col0 + r) * K + sslot * 8;
    }
    int ldsw = wid * 1024;     // wave-uniform chunk within each 8KB issue region

    // read-side byte offsets (within a ks block): row*64 + ((lane>>4)^(lane&3))*16
    int rslot = ((lane >> 4) ^ (lane & 3)) << 4;
    int aro = (wm * 128 + (lane & 15)) * 64 + rslot;   // + fr*1024 + ks*16384
    int bro = (wn * 64 + (lane & 15)) * 64 + rslot;    // + fc*1024 + ks*16384 + 32768

    #define STAGE_A(buf, kt, ks) { \
        gload16(A + aoff[0] + (kt) + (ks) * 32, (buf) + (ks) * 16384 + ldsw); \
        gload16(A + aoff[1] + (kt) + (ks) * 32, (buf) + (ks) * 16384 + 8192 + ldsw); }
    #define STAGE_B(buf, kt, ks) { \
        gload16(wp + boff[0] + (kt) + (ks) * 32, (buf) + 32768 + (ks) * 16384 + ldsw); \
        gload16(wp + boff[1] + (kt) + (ks) * 32, (buf) + 32768 + (ks) * 16384 + 8192 + ldsw); }

    // prologue: tile 0 fully staged (order: Aks0,Bks0,Aks1,Bks1)
    STAGE_A(lds, 0, 0); STAGE_B(lds, 0, 0);
    STAGE_A(lds, 0, 1); STAGE_B(lds, 0, 1);
    WAIT_VM4();          // ks0 landed; ks1 (4 loads) in flight
    BAR();

    f32x4 acc[8][4] = {};

    for (int t = 0; t < NT; ++t) {
        char* cur = lds + (t & 1) * 65536;
        char* nxt = lds + ((t + 1) & 1) * 65536;
        int kt1 = (t + 1) * 64;
        bool pre = (t + 1 < NT);
        s16x8 av[4], bv[4], av2[4];

        // ---- ph1: ks0, frag-rows 0-3 (8 ds_read) ; stage Aks0(t+1)
        #pragma unroll
        for (int f = 0; f < 4; ++f) av[f] = *(const s16x8*)(cur + aro + f * 1024);
        #pragma unroll
        for (int f = 0; f < 4; ++f) bv[f] = *(const s16x8*)(cur + 32768 + bro + f * 1024);
        if (pre) STAGE_A(nxt, kt1, 0);
        BAR(); WAIT_LGKM0();
        __builtin_amdgcn_s_setprio(1);
        #pragma unroll
        for (int j = 0; j < 4; ++j)
            #pragma unroll
            for (int i = 0; i < 4; ++i)
                acc[i][j] = __builtin_amdgcn_mfma_f32_16x16x32_bf16(av[i], bv[j], acc[i][j], 0, 0, 0);
        __builtin_amdgcn_s_setprio(0);
        BAR();

        // ---- ph2: ks0, frag-rows 4-7 (4 ds_read) ; stage Bks0(t+1)
        #pragma unroll
        for (int f = 0; f < 4; ++f) av2[f] = *(const s16x8*)(cur + aro + (f + 4) * 1024);
        if (pre) STAGE_B(nxt, kt1, 0);
        BAR(); WAIT_LGKM0();
        __builtin_amdgcn_s_setprio(1);
        #pragma unroll
        for (int j = 0; j < 4; ++j)
            #pragma unroll
            for (int i = 0; i < 4; ++i)
                acc[i + 4][j] = __builtin_amdgcn_mfma_f32_16x16x32_bf16(av2[i], bv[j], acc[i + 4][j], 0, 0, 0);
        __builtin_amdgcn_s_setprio(0);
        if (pre) { WAIT_VM4(); } else { WAIT_VM0(); }   // ks1(t) landed
        BAR();

        // ---- ph3: ks1, frag-rows 0-3 (8 ds_read) ; stage Aks1(t+1)
        #pragma unroll
        for (int f = 0; f < 4; ++f) av[f] = *(const s16x8*)(cur + 16384 + aro + f * 1024);
        #pragma unroll
        for (int f = 0; f < 4; ++f) bv[f] = *(const s16x8*)(cur + 32768 + 16384 + bro + f * 1024);
        if (pre) STAGE_A(nxt, kt1, 1);
        BAR(); WAIT_LGKM0();
        __builtin_amdgcn_s_setprio(1);
        #pragma unroll
        for (int j = 0; j < 4; ++j)
            #pragma unroll
            for (int i = 0; i < 4; ++i)
                acc[i][j] = __builtin_amdgcn_mfma_f32_16x16x32_bf16(av[i], bv[j], acc[i][j], 0, 0, 0);
        __builtin_amdgcn_s_setprio(0);
        BAR();

        // ---- ph4: ks1, frag-rows 4-7 (4 ds_read) ; stage Bks1(t+1)
        #pragma unroll
        for (int f = 0; f < 4; ++f) av2[f] = *(const s16x8*)(cur + 16384 + aro + (f + 4) * 1024);
        if (pre) STAGE_B(nxt, kt1, 1);
        BAR(); WAIT_LGKM0();
        __builtin_amdgcn_s_setprio(1);
        #pragma unroll
        for (int j = 0; j < 4; ++j)
            #pragma unroll
            for (int i = 0; i < 4; ++i)
                acc[i + 4][j] = __builtin_amdgcn_mfma_f32_16x16x32_bf16(av2[i], bv[j], acc[i + 4][j], 0, 0, 0);
        __builtin_amdgcn_s_setprio(0);
        if (pre) WAIT_VM4();                            // ks0(t+1) landed
        BAR();
    }
    #undef STAGE_A
    #undef STAGE_B

    // ---- epilogue: silu(w1-frag)*w3-frag; cols interleaved at 16 granule
    #pragma unroll
    for (int i = 0; i < 8; ++i) {
        int row = row0 + wm * 128 + i * 16 + ((lane >> 4) << 2);
        #pragma unroll
        for (int m = 0; m < 2; ++m) {
            int hc = ((col0 + wn * 64) >> 1) + m * 16 + (lane & 15);
            #pragma unroll
            for (int rg = 0; rg < 4; ++rg) {
                float a1 = acc[i][2 * m][rg];
                float a3 = acc[i][2 * m + 1][rg];
                float hv = (a1 / (1.f + __expf(-a1))) * a3;
                H[(size_t)(row + rg) * HIDN + hc] = f2bf(hv);
            }
        }
    }
}

// ------------- gemm2: m97 128x128 structure (known 874 TF) -------------
__global__ __launch_bounds__(256, 3)
void gemm2_kernel(const uint16_t* __restrict__ Hg,
                  const uint16_t* __restrict__ W2, uint16_t* __restrict__ H2,
                  const int* __restrict__ offs) {
    __shared__ __align__(16) char lds[32768];
    char* As = lds;
    char* Bs = lds + 16384;

    const int K = HIDN;
    int row0 = blockIdx.y * 128;
    int rsh = row0 - offs[NEXP];
    int e;
    if (rsh >= 0) {
        if (rsh >= 2 * T_TOK) return;
        e = NEXP + (rsh >> 12);
    } else {
        e = 0;
        while (row0 >= offs[e + 1]) ++e;
    }
    const uint16_t* b2 = W2 + (size_t)e * DIMD * HIDN;
    int col0 = blockIdx.x * 128;

    int tid = threadIdx.x, lane = tid & 63;
    int wv = tid >> 6, wm = wv >> 1, wn = wv & 1;

    f32x4 acc[4][4] = {};

    for (int kt = 0; kt < K; kt += 64) {
        __syncthreads();
        stage128x64(Hg + (size_t)row0 * K + kt, K, As, wv, lane);
        stage128x64(b2 + (size_t)col0 * K + kt, K, Bs, wv, lane);
        __syncthreads();

        #pragma unroll
        for (int s = 0; s < 2; ++s) {
            int cb = s * 64 + ((lane >> 4) << 4);
            s16x8 av[4];
            #pragma unroll
            for (int i = 0; i < 4; ++i)
                av[i] = *(const s16x8*)(As + swz(wm * 64 + i * 16 + (lane & 15), cb));
            #pragma unroll
            for (int j = 0; j < 4; ++j) {
                s16x8 bv = *(const s16x8*)(Bs + swz(wn * 64 + j * 16 + (lane & 15), cb));
                #pragma unroll
                for (int i = 0; i < 4; ++i)
                    acc[i][j] = __builtin_amdgcn_mfma_f32_16x16x32_bf16(av[i], bv, acc[i][j], 0, 0, 0);
            }
        }
    }

    #pragma unroll
    for (int i = 0; i < 4; ++i) {
        #pragma unroll
        for (int j = 0; j < 4; ++j) {
            #pragma unroll
            for (int rg = 0; rg < 4; ++rg) {
                int row = row0 + wm * 64 + i * 16 + ((lane >> 4) << 2) + rg;
                int col = col0 + wn * 64 + j * 16 + (lane & 15);
                H2[(size_t)row * DIMD + col] = f2bf(acc[i][j][rg]);
            }
        }
    }
}

// ---------------- launch ----------------

extern "C" void kernel_launch(void* const* d_in, const int* in_sizes, int n_in,
                              void* d_out, int out_size, void* d_ws, size_t ws_size,
                              hipStream_t stream) {
    const float* x   = (const float*)d_in[0];
    const float* rw  = (const float*)d_in[1];
    const float* eb  = (const float*)d_in[2];
    const float* w1  = (const float*)d_in[3];
    const float* w3  = (const float*)d_in[4];
    const float* w2  = (const float*)d_in[5];
    const float* sw1 = (const float*)d_in[6];
    const float* sw3 = (const float*)d_in[7];
    const float* sw2 = (const float*)d_in[8];
    float* out = (float*)d_out;

    const size_t EW = (size_t)NEXP * HIDN * DIMD;
    const size_t SW = (size_t)2 * HIDN * DIMD;

    char* ws = (char*)d_ws;
    size_t off = 0;
    auto alloc = [&](size_t b) { char* p = ws + off; off = (off + b + 255) & ~(size_t)255; return p; };
    uint16_t* xb    = (uint16_t*)alloc((size_t)T_TOK * DIMD * 2);
    uint16_t* Hg    = (uint16_t*)alloc((size_t)RROWS * HIDN * 2);
    uint16_t* H2    = (uint16_t*)alloc((size_t)RROWS * DIMD * 2);
    uint16_t* w13   = (uint16_t*)alloc((size_t)10 * 4096 * 1024 * 2);  // interleaved, 10 experts
    uint16_t* w2all = (uint16_t*)alloc((EW + SW) * 2);
    int*   sel    = (int*)  alloc(T_TOK * 2 * 4);
    float* wgt    = (float*)alloc(T_TOK * 2 * 4);
    int*   row_of = (int*)  alloc(T_TOK * 2 * 4);
    int*   tok    = (int*)  alloc(RROWS * 4);
    int*   cnt    = (int*)  alloc(64);
    int*   fill   = (int*)  alloc(64);
    int*   offs   = (int*)  alloc(64);

    hipMemsetAsync(cnt, 0, 64, stream);
    hipMemsetAsync(fill, 0, 64, stream);
    hipMemsetAsync(tok, 0, RROWS * 4, stream);   // pad rows -> token 0 (harmless)

    CvtArgs ca;
    ca.s[0] = w1;  ca.d[0] = w13;                           ca.nq[0] = (int)(EW / 4); ca.mode[0] = 1;
    ca.s[1] = sw1; ca.d[1] = w13 + (size_t)8 * 4096 * 1024; ca.nq[1] = (int)(SW / 4); ca.mode[1] = 1;
    ca.s[2] = w3;  ca.d[2] = w13;                           ca.nq[2] = (int)(EW / 4); ca.mode[2] = 2;
    ca.s[3] = sw3; ca.d[3] = w13 + (size_t)8 * 4096 * 1024; ca.nq[3] = (int)(SW / 4); ca.mode[3] = 2;
    ca.s[4] = w2;  ca.d[4] = w2all;                         ca.nq[4] = (int)(EW / 4); ca.mode[4] = 0;
    ca.s[5] = sw2; ca.d[5] = w2all + EW;                    ca.nq[5] = (int)(SW / 4); ca.mode[5] = 0;
    ca.s[6] = x;   ca.d[6] = xb;                            ca.nq[6] = T_TOK * DIMD / 4; ca.mode[6] = 0;
    cvt_all_kernel<<<2048, 256, 0, stream>>>(ca);

    router_kernel<<<128, 256, 0, stream>>>(x, rw, eb, sel, wgt, cnt);
    offs_kernel<<<1, 1, 0, stream>>>(cnt, offs);
    assign_kernel<<<64, 256, 0, stream>>>(sel, offs, fill, row_of, tok);

    gemm13_8p<<<dim3(16, RROWS / 256), 512, 0, stream>>>(xb, tok, w13, Hg, offs);
    gemm2_kernel<<<dim3(DIMD / 128, RROWS / 128), 256, 0, stream>>>(Hg, w2all, H2, offs);

    combine_kernel<<<T_TOK, 128, 0, stream>>>(H2, row_of, wgt, offs, out);
}

// Round 9
// 484.460 us; speedup vs baseline: 1.0759x; 1.0163x over previous
//
#include <hip/hip_runtime.h>
#include <stdint.h>

#define T_TOK 4096
#define DIMD  1024
#define HIDN  2048
#define NEXP  8
#define RMAX  10240                 // routed: 8192 slots + 8*256 alignment pad
#define RROWS (RMAX + 2 * T_TOK)    // 18432 = 72*256 = 144*128 rows total

typedef float f32x4 __attribute__((ext_vector_type(4)));
typedef short s16x8 __attribute__((ext_vector_type(8)));

__device__ __forceinline__ uint16_t f2bf(float f) {
    uint32_t u = __builtin_bit_cast(uint32_t, f);
    u += 0x7fffu + ((u >> 16) & 1u);
    return (uint16_t)(u >> 16);
}
__device__ __forceinline__ float bf2f(uint32_t h) {
    return __builtin_bit_cast(float, h << 16);
}
__device__ __forceinline__ uint32_t pk2(float a, float b) {
    return (uint32_t)f2bf(a) | ((uint32_t)f2bf(b) << 16);
}
// m97-style swizzle (gemm2): 128B row pitch, XOR row bits into 16B granule
__device__ __forceinline__ int swz(int r, int cbyte) {
    return r * 128 + (cbyte ^ ((r & 7) << 4));
}
__device__ __forceinline__ void gload16(const void* g, void* l) {
    __builtin_amdgcn_global_load_lds(
        (const __attribute__((address_space(1))) void*)g,
        (__attribute__((address_space(3))) void*)l, 16, 0, 0);
}
#define BAR()        asm volatile("s_barrier" ::: "memory")
#define WAIT_VM4()   asm volatile("s_waitcnt vmcnt(4)" ::: "memory")
#define WAIT_VM0()   asm volatile("s_waitcnt vmcnt(0)" ::: "memory")
#define WAIT_LGKM0() asm volatile("s_waitcnt lgkmcnt(0)" ::: "memory")

// Stage a 128x64 bf16 tile (16KB) into LDS, m97 layout (gemm2 only).
__device__ __forceinline__ void stage128x64(const uint16_t* gbase, int ldk,
                                            char* lds, int wv, int lane) {
    #pragma unroll
    for (int i = 0; i < 4; ++i) {
        int s = (wv * 4 + i) * 64 + lane;
        int row = s >> 3;
        int cb = ((s & 7) << 4) ^ ((row & 7) << 4);
        gload16(gbase + (size_t)row * ldk + (cb >> 1), lds + ((wv * 4 + i) << 10));
    }
}

// ---------------- small kernels ----------------

struct CvtArgs {
    const float* s[7];
    uint16_t*    d[7];
    int          nq[7];
    int          mode[7];   // 0 straight, 1 w1->interleaved, 2 w3->interleaved
};

// w13 interleave: dest N-row n' = (n>>4)*32 + (mode==2?16:0) + (n&15): within each
// 32-row granule rows 0-15 are w1, 16-31 are w3 of the same 16 hidden channels.
__global__ void cvt_all_kernel(CvtArgs a) {
    int base = blockIdx.x * blockDim.x + threadIdx.x;
    int stride = gridDim.x * blockDim.x;
    #pragma unroll
    for (int seg = 0; seg < 7; ++seg) {
        const float4* sp = (const float4*)a.s[seg];
        uint2* dp = (uint2*)a.d[seg];
        int n = a.nq[seg];
        int mode = a.mode[seg];
        for (int i = base; i < n; i += stride) {
            float4 v = sp[i];
            uint2 o; o.x = pk2(v.x, v.y); o.y = pk2(v.z, v.w);
            int di = i;
            if (mode) {
                int e = i >> 19;            // quads per src expert: 2048*256 = 2^19
                int rem = i & 524287;
                int nr = rem >> 8;          // source N row
                int kq = rem & 255;
                int np = ((nr >> 4) << 5) + ((mode == 2) ? 16 : 0) + (nr & 15);
                di = (e << 20) + (np << 8) + kq;
            }
            dp[di] = o;
        }
    }
}

// Router: 128 blocks x 256 thr; rw staged in LDS; 1 wave = 8 tokens.
__global__ __launch_bounds__(256)
void router_kernel(const float* __restrict__ x, const float* __restrict__ rw,
                   const float* __restrict__ bias,
                   int* __restrict__ sel, float* __restrict__ wgt,
                   int* __restrict__ cnt) {
    __shared__ float rws[NEXP * DIMD];
    int tid = threadIdx.x;
    for (int i = tid; i < NEXP * DIMD / 4; i += 256)
        ((float4*)rws)[i] = ((const float4*)rw)[i];
    __syncthreads();

    int wid = tid >> 6, lane = tid & 63;
    float b[NEXP];
    #pragma unroll
    for (int e = 0; e < NEXP; ++e) b[e] = bias[e];

    int t0 = (blockIdx.x * 4 + wid) * 8;
    for (int j = 0; j < 8; ++j) {
        int t = t0 + j;
        const float4* xr = (const float4*)(x + (size_t)t * DIMD);
        float p[NEXP] = {};
        #pragma unroll
        for (int c = 0; c < 4; ++c) {
            float4 xv = xr[c * 64 + lane];
            #pragma unroll
            for (int e = 0; e < NEXP; ++e) {
                float4 wv = *(const float4*)(rws + e * DIMD + c * 256 + lane * 4);
                p[e] += xv.x * wv.x + xv.y * wv.y + xv.z * wv.z + xv.w * wv.w;
            }
        }
        #pragma unroll
        for (int off = 32; off >= 1; off >>= 1) {
            #pragma unroll
            for (int e = 0; e < NEXP; ++e) p[e] += __shfl_xor(p[e], off, 64);
        }
        if (lane == 0) {
            #pragma unroll
            for (int e = 0; e < NEXP; ++e) p[e] += b[e];
            float l0 = -1e30f; int i0 = 0;
            #pragma unroll
            for (int e = 0; e < NEXP; ++e) { if (p[e] > l0) { l0 = p[e]; i0 = e; } }
            float l1 = -1e30f; int i1 = 0;
            #pragma unroll
            for (int e = 0; e < NEXP; ++e) { if (e == i0) continue; if (p[e] > l1) { l1 = p[e]; i1 = e; } }
            float e1 = expf(l1 - l0);      // l0 >= l1 -> e1 <= 1
            float d = 1.f + e1;
            sel[t * 2] = i0; sel[t * 2 + 1] = i1;
            wgt[t * 2] = 1.f / d; wgt[t * 2 + 1] = e1 / d;
            atomicAdd(&cnt[i0], 1);
            atomicAdd(&cnt[i1], 1);
        }
    }
}

__global__ void offs_kernel(const int* __restrict__ cnt, int* __restrict__ offs) {
    if (threadIdx.x == 0 && blockIdx.x == 0) {
        int o = 0;
        for (int e = 0; e < NEXP; ++e) { offs[e] = o; o += (cnt[e] + 255) & ~255; }  // 256-align
        offs[NEXP] = o;
    }
}

__global__ void assign_kernel(const int* __restrict__ sel, const int* __restrict__ offs,
                              int* __restrict__ fill, int* __restrict__ row_of,
                              int* __restrict__ tok) {
    int i = blockIdx.x * blockDim.x + threadIdx.x;
    if (i < 2 * T_TOK) {
        int e = sel[i];
        int r = offs[e] + atomicAdd(&fill[e], 1);
        row_of[i] = r;
        tok[r] = i >> 1;
    } else if (i < 4 * T_TOK) {
        int j = i - 2 * T_TOK;                       // 0..8191: shared rows
        tok[offs[NEXP] + j] = j & (T_TOK - 1);
    }
}

// out[t] = w0*H2[r0] + w1*H2[r1] + H2[s0] + H2[s1]  (pure write)
__global__ void combine_kernel(const uint16_t* __restrict__ H2, const int* __restrict__ row_of,
                               const float* __restrict__ wgt, const int* __restrict__ offs,
                               float* __restrict__ out) {
    int t = blockIdx.x;
    int c = threadIdx.x * 8;   // 128 threads * 8 cols
    int r0 = row_of[t * 2], r1 = row_of[t * 2 + 1];
    int s0 = offs[NEXP] + t, s1 = s0 + T_TOK;
    float w0 = wgt[t * 2], w1 = wgt[t * 2 + 1];
    uint4 a = *(const uint4*)(H2 + (size_t)r0 * DIMD + c);
    uint4 b = *(const uint4*)(H2 + (size_t)r1 * DIMD + c);
    uint4 u = *(const uint4*)(H2 + (size_t)s0 * DIMD + c);
    uint4 v = *(const uint4*)(H2 + (size_t)s1 * DIMD + c);
    float4 o0, o1;
    o0.x = w0 * bf2f(a.x & 0xffffu) + w1 * bf2f(b.x & 0xffffu) + bf2f(u.x & 0xffffu) + bf2f(v.x & 0xffffu);
    o0.y = w0 * bf2f(a.x >> 16)     + w1 * bf2f(b.x >> 16)     + bf2f(u.x >> 16)     + bf2f(v.x >> 16);
    o0.z = w0 * bf2f(a.y & 0xffffu) + w1 * bf2f(b.y & 0xffffu) + bf2f(u.y & 0xffffu) + bf2f(v.y & 0xffffu);
    o0.w = w0 * bf2f(a.y >> 16)     + w1 * bf2f(b.y >> 16)     + bf2f(u.y >> 16)     + bf2f(v.y >> 16);
    o1.x = w0 * bf2f(a.z & 0xffffu) + w1 * bf2f(b.z & 0xffffu) + bf2f(u.z & 0xffffu) + bf2f(v.z & 0xffffu);
    o1.y = w0 * bf2f(a.z >> 16)     + w1 * bf2f(b.z >> 16)     + bf2f(u.z >> 16)     + bf2f(v.z >> 16);
    o1.z = w0 * bf2f(a.w & 0xffffu) + w1 * bf2f(b.w & 0xffffu) + bf2f(u.w & 0xffffu) + bf2f(v.w & 0xffffu);
    o1.w = w0 * bf2f(a.w >> 16)     + w1 * bf2f(b.w >> 16)     + bf2f(u.w >> 16)     + bf2f(v.w >> 16);
    float* o = out + (size_t)t * DIMD + c;
    *(float4*)o = o0;
    *(float4*)(o + 4) = o1;
}

// ------------- gemm13: 256x256 tile, BK=64, 4-phase counted-vmcnt pipeline -------------
// 512 thr = 8 waves (2M x 4N); per-wave C = 128x64 = acc[8][4] frags.
// LDS: 2 bufs x (A 32K + B 32K); each 32K = 2 ks-blocks of [256 rows][64B].
// Swizzle (bank fix vs r8): slot(row, khi16) = khi16 ^ ((row>>1)&3) -> lanes 0-15
// hit each 4-bank group exactly twice (2-way = free, m136). Write side: LDS is
// linear; source chunk = (lane&3) ^ ((tid>>3)&3) since (R>>1)&3 == (tid>>3)&3.
// Ledger (loads/thread): entry outstanding = 4 (= ks1(t)). ph1 +2 (Aks0 t+1),
// ph2 +2 (Bks0 t+1) -> vmcnt(4) lands ks1(t) before ph3 reads. ph3 +2 (Aks1 t+1),
// ph4 +2 (Bks1 t+1) -> vmcnt(4) lands ks0(t+1) before next tile. Never drains.
__global__ __launch_bounds__(512, 2)
void gemm13_8p(const uint16_t* __restrict__ A, const int* __restrict__ tok,
               const uint16_t* __restrict__ W, uint16_t* __restrict__ H,
               const int* __restrict__ offs) {
    constexpr int K = DIMD;       // 1024
    constexpr int NT = K / 64;    // 16 K-tiles
    __shared__ __align__(16) char lds[131072];

    int row0 = blockIdx.y * 256;
    int rsh = row0 - offs[NEXP];
    int e;
    if (rsh >= 0) {
        if (rsh >= 2 * T_TOK) return;
        e = NEXP + (rsh >> 12);
    } else {
        e = 0;
        while (row0 >= offs[e + 1]) ++e;
    }
    const uint16_t* wp = W + (size_t)e * (4096ull * 1024ull);
    int col0 = blockIdx.x * 256;

    int tid = threadIdx.x, lane = tid & 63, wid = tid >> 6;
    int wm = wid >> 2, wn = wid & 3;

    // staging: issue i covers rows i*128 + (tid>>2); LDS slot = lane&3 holds
    // source k-chunk (lane&3) ^ ((tid>>3)&3)  [= slot ^ ((R>>1)&3)]
    int sslot = (lane & 3) ^ ((tid >> 3) & 3);
    uint32_t aoff[2], boff[2];
    #pragma unroll
    for (int i = 0; i < 2; ++i) {
        int r = i * 128 + (tid >> 2);
        int garow = tok[row0 + r];
        aoff[i] = (uint32_t)garow * K + sslot * 8;
        boff[i] = (uint32_t)(col0 + r) * K + sslot * 8;
    }
    int ldsw = wid * 1024;     // wave-uniform chunk within each 8KB issue region

    // read side: row r', k-chunk khi16 -> slot khi16 ^ ((r'>>1)&3); for our row
    // maps (r' = base16 + lane&15) that is khi16 ^ ((lane>>1)&3), frag-independent
    int rslot = (((lane >> 4) ^ ((lane >> 1) & 3)) << 4);
    int aro = (wm * 128 + (lane & 15)) * 64 + rslot;   // + fr*1024 + ks*16384
    int bro = (wn * 64 + (lane & 15)) * 64 + rslot;    // + fc*1024 + ks*16384 + 32768

    #define STAGE_A(buf, kt, ks) { \
        gload16(A + aoff[0] + (kt) + (ks) * 32, (buf) + (ks) * 16384 + ldsw); \
        gload16(A + aoff[1] + (kt) + (ks) * 32, (buf) + (ks) * 16384 + 8192 + ldsw); }
    #define STAGE_B(buf, kt, ks) { \
        gload16(wp + boff[0] + (kt) + (ks) * 32, (buf) + 32768 + (ks) * 16384 + ldsw); \
        gload16(wp + boff[1] + (kt) + (ks) * 32, (buf) + 32768 + (ks) * 16384 + 8192 + ldsw); }

    // prologue: tile 0 fully staged (order: Aks0,Bks0,Aks1,Bks1)
    STAGE_A(lds, 0, 0); STAGE_B(lds, 0, 0);
    STAGE_A(lds, 0, 1); STAGE_B(lds, 0, 1);
    WAIT_VM4();          // ks0 landed; ks1 (4 loads) in flight
    BAR();

    f32x4 acc[8][4] = {};

    for (int t = 0; t < NT; ++t) {
        char* cur = lds + (t & 1) * 65536;
        char* nxt = lds + ((t + 1) & 1) * 65536;
        int kt1 = (t + 1) * 64;
        bool pre = (t + 1 < NT);
        s16x8 av[4], bv[4], av2[4];

        // ---- ph1: ks0, frag-rows 0-3 (8 ds_read) ; stage Aks0(t+1)
        #pragma unroll
        for (int f = 0; f < 4; ++f) av[f] = *(const s16x8*)(cur + aro + f * 1024);
        #pragma unroll
        for (int f = 0; f < 4; ++f) bv[f] = *(const s16x8*)(cur + 32768 + bro + f * 1024);
        if (pre) STAGE_A(nxt, kt1, 0);
        BAR(); WAIT_LGKM0();
        __builtin_amdgcn_s_setprio(1);
        #pragma unroll
        for (int j = 0; j < 4; ++j)
            #pragma unroll
            for (int i = 0; i < 4; ++i)
                acc[i][j] = __builtin_amdgcn_mfma_f32_16x16x32_bf16(av[i], bv[j], acc[i][j], 0, 0, 0);
        __builtin_amdgcn_s_setprio(0);
        BAR();

        // ---- ph2: ks0, frag-rows 4-7 (4 ds_read) ; stage Bks0(t+1)
        #pragma unroll
        for (int f = 0; f < 4; ++f) av2[f] = *(const s16x8*)(cur + aro + (f + 4) * 1024);
        if (pre) STAGE_B(nxt, kt1, 0);
        BAR(); WAIT_LGKM0();
        __builtin_amdgcn_s_setprio(1);
        #pragma unroll
        for (int j = 0; j < 4; ++j)
            #pragma unroll
            for (int i = 0; i < 4; ++i)
                acc[i + 4][j] = __builtin_amdgcn_mfma_f32_16x16x32_bf16(av2[i], bv[j], acc[i + 4][j], 0, 0, 0);
        __builtin_amdgcn_s_setprio(0);
        if (pre) { WAIT_VM4(); } else { WAIT_VM0(); }   // ks1(t) landed
        BAR();

        // ---- ph3: ks1, frag-rows 0-3 (8 ds_read) ; stage Aks1(t+1)
        #pragma unroll
        for (int f = 0; f < 4; ++f) av[f] = *(const s16x8*)(cur + 16384 + aro + f * 1024);
        #pragma unroll
        for (int f = 0; f < 4; ++f) bv[f] = *(const s16x8*)(cur + 32768 + 16384 + bro + f * 1024);
        if (pre) STAGE_A(nxt, kt1, 1);
        BAR(); WAIT_LGKM0();
        __builtin_amdgcn_s_setprio(1);
        #pragma unroll
        for (int j = 0; j < 4; ++j)
            #pragma unroll
            for (int i = 0; i < 4; ++i)
                acc[i][j] = __builtin_amdgcn_mfma_f32_16x16x32_bf16(av[i], bv[j], acc[i][j], 0, 0, 0);
        __builtin_amdgcn_s_setprio(0);
        BAR();

        // ---- ph4: ks1, frag-rows 4-7 (4 ds_read) ; stage Bks1(t+1)
        #pragma unroll
        for (int f = 0; f < 4; ++f) av2[f] = *(const s16x8*)(cur + 16384 + aro + (f + 4) * 1024);
        if (pre) STAGE_B(nxt, kt1, 1);
        BAR(); WAIT_LGKM0();
        __builtin_amdgcn_s_setprio(1);
        #pragma unroll
        for (int j = 0; j < 4; ++j)
            #pragma unroll
            for (int i = 0; i < 4; ++i)
                acc[i + 4][j] = __builtin_amdgcn_mfma_f32_16x16x32_bf16(av2[i], bv[j], acc[i + 4][j], 0, 0, 0);
        __builtin_amdgcn_s_setprio(0);
        if (pre) WAIT_VM4();                            // ks0(t+1) landed
        BAR();
    }
    #undef STAGE_A
    #undef STAGE_B

    // ---- epilogue: silu(w1-frag)*w3-frag; cols interleaved at 16 granule
    #pragma unroll
    for (int i = 0; i < 8; ++i) {
        int row = row0 + wm * 128 + i * 16 + ((lane >> 4) << 2);
        #pragma unroll
        for (int m = 0; m < 2; ++m) {
            int hc = ((col0 + wn * 64) >> 1) + m * 16 + (lane & 15);
            #pragma unroll
            for (int rg = 0; rg < 4; ++rg) {
                float a1 = acc[i][2 * m][rg];
                float a3 = acc[i][2 * m + 1][rg];
                float hv = (a1 / (1.f + __expf(-a1))) * a3;
                H[(size_t)(row + rg) * HIDN + hc] = f2bf(hv);
            }
        }
    }
}

// ------------- gemm2: m97 128x128 structure (known 874 TF) -------------
__global__ __launch_bounds__(256, 3)
void gemm2_kernel(const uint16_t* __restrict__ Hg,
                  const uint16_t* __restrict__ W2, uint16_t* __restrict__ H2,
                  const int* __restrict__ offs) {
    __shared__ __align__(16) char lds[32768];
    char* As = lds;
    char* Bs = lds + 16384;

    const int K = HIDN;
    int row0 = blockIdx.y * 128;
    int rsh = row0 - offs[NEXP];
    int e;
    if (rsh >= 0) {
        if (rsh >= 2 * T_TOK) return;
        e = NEXP + (rsh >> 12);
    } else {
        e = 0;
        while (row0 >= offs[e + 1]) ++e;
    }
    const uint16_t* b2 = W2 + (size_t)e * DIMD * HIDN;
    int col0 = blockIdx.x * 128;

    int tid = threadIdx.x, lane = tid & 63;
    int wv = tid >> 6, wm = wv >> 1, wn = wv & 1;

    f32x4 acc[4][4] = {};

    for (int kt = 0; kt < K; kt += 64) {
        __syncthreads();
        stage128x64(Hg + (size_t)row0 * K + kt, K, As, wv, lane);
        stage128x64(b2 + (size_t)col0 * K + kt, K, Bs, wv, lane);
        __syncthreads();

        #pragma unroll
        for (int s = 0; s < 2; ++s) {
            int cb = s * 64 + ((lane >> 4) << 4);
            s16x8 av[4];
            #pragma unroll
            for (int i = 0; i < 4; ++i)
                av[i] = *(const s16x8*)(As + swz(wm * 64 + i * 16 + (lane & 15), cb));
            #pragma unroll
            for (int j = 0; j < 4; ++j) {
                s16x8 bv = *(const s16x8*)(Bs + swz(wn * 64 + j * 16 + (lane & 15), cb));
                #pragma unroll
                for (int i = 0; i < 4; ++i)
                    acc[i][j] = __builtin_amdgcn_mfma_f32_16x16x32_bf16(av[i], bv, acc[i][j], 0, 0, 0);
            }
        }
    }

    #pragma unroll
    for (int i = 0; i < 4; ++i) {
        #pragma unroll
        for (int j = 0; j < 4; ++j) {
            #pragma unroll
            for (int rg = 0; rg < 4; ++rg) {
                int row = row0 + wm * 64 + i * 16 + ((lane >> 4) << 2) + rg;
                int col = col0 + wn * 64 + j * 16 + (lane & 15);
                H2[(size_t)row * DIMD + col] = f2bf(acc[i][j][rg]);
            }
        }
    }
}

// ---------------- launch ----------------

extern "C" void kernel_launch(void* const* d_in, const int* in_sizes, int n_in,
                              void* d_out, int out_size, void* d_ws, size_t ws_size,
                              hipStream_t stream) {
    const float* x   = (const float*)d_in[0];
    const float* rw  = (const float*)d_in[1];
    const float* eb  = (const float*)d_in[2];
    const float* w1  = (const float*)d_in[3];
    const float* w3  = (const float*)d_in[4];
    const float* w2  = (const float*)d_in[5];
    const float* sw1 = (const float*)d_in[6];
    const float* sw3 = (const float*)d_in[7];
    const float* sw2 = (const float*)d_in[8];
    float* out = (float*)d_out;

    const size_t EW = (size_t)NEXP * HIDN * DIMD;
    const size_t SW = (size_t)2 * HIDN * DIMD;

    char* ws = (char*)d_ws;
    size_t off = 0;
    auto alloc = [&](size_t b) { char* p = ws + off; off = (off + b + 255) & ~(size_t)255; return p; };
    uint16_t* xb    = (uint16_t*)alloc((size_t)T_TOK * DIMD * 2);
    uint16_t* Hg    = (uint16_t*)alloc((size_t)RROWS * HIDN * 2);
    uint16_t* H2    = (uint16_t*)alloc((size_t)RROWS * DIMD * 2);
    uint16_t* w13   = (uint16_t*)alloc((size_t)10 * 4096 * 1024 * 2);  // interleaved, 10 experts
    uint16_t* w2all = (uint16_t*)alloc((EW + SW) * 2);
    int*   sel    = (int*)  alloc(T_TOK * 2 * 4);
    float* wgt    = (float*)alloc(T_TOK * 2 * 4);
    int*   row_of = (int*)  alloc(T_TOK * 2 * 4);
    int*   tok    = (int*)  alloc(RROWS * 4);
    int*   cnt    = (int*)  alloc(64);
    int*   fill   = (int*)  alloc(64);
    int*   offs   = (int*)  alloc(64);

    hipMemsetAsync(cnt, 0, 64, stream);
    hipMemsetAsync(fill, 0, 64, stream);
    hipMemsetAsync(tok, 0, RROWS * 4, stream);   // pad rows -> token 0 (harmless)

    CvtArgs ca;
    ca.s[0] = w1;  ca.d[0] = w13;                           ca.nq[0] = (int)(EW / 4); ca.mode[0] = 1;
    ca.s[1] = sw1; ca.d[1] = w13 + (size_t)8 * 4096 * 1024; ca.nq[1] = (int)(SW / 4); ca.mode[1] = 1;
    ca.s[2] = w3;  ca.d[2] = w13;                           ca.nq[2] = (int)(EW / 4); ca.mode[2] = 2;
    ca.s[3] = sw3; ca.d[3] = w13 + (size_t)8 * 4096 * 1024; ca.nq[3] = (int)(SW / 4); ca.mode[3] = 2;
    ca.s[4] = w2;  ca.d[4] = w2all;                         ca.nq[4] = (int)(EW / 4); ca.mode[4] = 0;
    ca.s[5] = sw2; ca.d[5] = w2all + EW;                    ca.nq[5] = (int)(SW / 4); ca.mode[5] = 0;
    ca.s[6] = x;   ca.d[6] = xb;                            ca.nq[6] = T_TOK * DIMD / 4; ca.mode[6] = 0;
    cvt_all_kernel<<<2048, 256, 0, stream>>>(ca);

    router_kernel<<<128, 256, 0, stream>>>(x, rw, eb, sel, wgt, cnt);
    offs_kernel<<<1, 1, 0, stream>>>(cnt, offs);
    assign_kernel<<<64, 256, 0, stream>>>(sel, offs, fill, row_of, tok);

    gemm13_8p<<<dim3(16, RROWS / 256), 512, 0, stream>>>(xb, tok, w13, Hg, offs);
    gemm2_kernel<<<dim3(DIMD / 128, RROWS / 128), 256, 0, stream>>>(Hg, w2all, H2, offs);

    combine_kernel<<<T_TOK, 128, 0, stream>>>(H2, row_of, wgt, offs, out);
}

// Round 10
// 483.634 us; speedup vs baseline: 1.0778x; 1.0017x over previous
//
#include <hip/hip_runtime.h>
#include <stdint.h>

#define T_TOK 4096
#define DIMD  1024
#define HIDN  2048
#define NEXP  8
#define RMAX  10240                 // routed: 8192 slots + 8*256 alignment pad
#define RROWS (RMAX + 2 * T_TOK)    // 18432 = 72*256 = 144*128 rows total

typedef float f32x4 __attribute__((ext_vector_type(4)));
typedef short s16x8 __attribute__((ext_vector_type(8)));

__device__ __forceinline__ uint16_t f2bf(float f) {
    uint32_t u = __builtin_bit_cast(uint32_t, f);
    u += 0x7fffu + ((u >> 16) & 1u);
    return (uint16_t)(u >> 16);
}
__device__ __forceinline__ float bf2f(uint32_t h) {
    return __builtin_bit_cast(float, h << 16);
}
__device__ __forceinline__ uint32_t pk2(float a, float b) {
    return (uint32_t)f2bf(a) | ((uint32_t)f2bf(b) << 16);
}
__device__ __forceinline__ void gload16(const void* g, void* l) {
    __builtin_amdgcn_global_load_lds(
        (const __attribute__((address_space(1))) void*)g,
        (__attribute__((address_space(3))) void*)l, 16, 0, 0);
}
#define BAR()        asm volatile("s_barrier" ::: "memory")
#define WAIT_VM4()   asm volatile("s_waitcnt vmcnt(4)" ::: "memory")
#define WAIT_VM0()   asm volatile("s_waitcnt vmcnt(0)" ::: "memory")
#define WAIT_LGKM0() asm volatile("s_waitcnt lgkmcnt(0)" ::: "memory")

// ---------------- small kernels ----------------

struct CvtArgs {
    const float* s[7];
    uint16_t*    d[7];
    int          nq[7];
    int          mode[7];   // 0 straight, 1 w1->interleaved, 2 w3->interleaved
};

// w13 interleave: dest N-row n' = (n>>4)*32 + (mode==2?16:0) + (n&15): within each
// 32-row granule rows 0-15 are w1, 16-31 are w3 of the same 16 hidden channels.
__global__ void cvt_all_kernel(CvtArgs a) {
    int base = blockIdx.x * blockDim.x + threadIdx.x;
    int stride = gridDim.x * blockDim.x;
    #pragma unroll
    for (int seg = 0; seg < 7; ++seg) {
        const float4* sp = (const float4*)a.s[seg];
        uint2* dp = (uint2*)a.d[seg];
        int n = a.nq[seg];
        int mode = a.mode[seg];
        for (int i = base; i < n; i += stride) {
            float4 v = sp[i];
            uint2 o; o.x = pk2(v.x, v.y); o.y = pk2(v.z, v.w);
            int di = i;
            if (mode) {
                int e = i >> 19;            // quads per src expert: 2048*256 = 2^19
                int rem = i & 524287;
                int nr = rem >> 8;          // source N row
                int kq = rem & 255;
                int np = ((nr >> 4) << 5) + ((mode == 2) ? 16 : 0) + (nr & 15);
                di = (e << 20) + (np << 8) + kq;
            }
            dp[di] = o;
        }
    }
}

// Router: 128 blocks x 256 thr; rw staged in LDS; 1 wave = 8 tokens.
__global__ __launch_bounds__(256)
void router_kernel(const float* __restrict__ x, const float* __restrict__ rw,
                   const float* __restrict__ bias,
                   int* __restrict__ sel, float* __restrict__ wgt,
                   int* __restrict__ cnt) {
    __shared__ float rws[NEXP * DIMD];
    int tid = threadIdx.x;
    for (int i = tid; i < NEXP * DIMD / 4; i += 256)
        ((float4*)rws)[i] = ((const float4*)rw)[i];
    __syncthreads();

    int wid = tid >> 6, lane = tid & 63;
    float b[NEXP];
    #pragma unroll
    for (int e = 0; e < NEXP; ++e) b[e] = bias[e];

    int t0 = (blockIdx.x * 4 + wid) * 8;
    for (int j = 0; j < 8; ++j) {
        int t = t0 + j;
        const float4* xr = (const float4*)(x + (size_t)t * DIMD);
        float p[NEXP] = {};
        #pragma unroll
        for (int c = 0; c < 4; ++c) {
            float4 xv = xr[c * 64 + lane];
            #pragma unroll
            for (int e = 0; e < NEXP; ++e) {
                float4 wv = *(const float4*)(rws + e * DIMD + c * 256 + lane * 4);
                p[e] += xv.x * wv.x + xv.y * wv.y + xv.z * wv.z + xv.w * wv.w;
            }
        }
        #pragma unroll
        for (int off = 32; off >= 1; off >>= 1) {
            #pragma unroll
            for (int e = 0; e < NEXP; ++e) p[e] += __shfl_xor(p[e], off, 64);
        }
        if (lane == 0) {
            #pragma unroll
            for (int e = 0; e < NEXP; ++e) p[e] += b[e];
            float l0 = -1e30f; int i0 = 0;
            #pragma unroll
            for (int e = 0; e < NEXP; ++e) { if (p[e] > l0) { l0 = p[e]; i0 = e; } }
            float l1 = -1e30f; int i1 = 0;
            #pragma unroll
            for (int e = 0; e < NEXP; ++e) { if (e == i0) continue; if (p[e] > l1) { l1 = p[e]; i1 = e; } }
            float e1 = expf(l1 - l0);      // l0 >= l1 -> e1 <= 1
            float d = 1.f + e1;
            sel[t * 2] = i0; sel[t * 2 + 1] = i1;
            wgt[t * 2] = 1.f / d; wgt[t * 2 + 1] = e1 / d;
            atomicAdd(&cnt[i0], 1);
            atomicAdd(&cnt[i1], 1);
        }
    }
}

__global__ void offs_kernel(const int* __restrict__ cnt, int* __restrict__ offs) {
    if (threadIdx.x == 0 && blockIdx.x == 0) {
        int o = 0;
        for (int e = 0; e < NEXP; ++e) { offs[e] = o; o += (cnt[e] + 255) & ~255; }  // 256-align
        offs[NEXP] = o;
    }
}

__global__ void assign_kernel(const int* __restrict__ sel, const int* __restrict__ offs,
                              int* __restrict__ fill, int* __restrict__ row_of,
                              int* __restrict__ tok) {
    int i = blockIdx.x * blockDim.x + threadIdx.x;
    if (i < 2 * T_TOK) {
        int e = sel[i];
        int r = offs[e] + atomicAdd(&fill[e], 1);
        row_of[i] = r;
        tok[r] = i >> 1;
    } else if (i < 4 * T_TOK) {
        int j = i - 2 * T_TOK;                       // 0..8191: shared rows
        tok[offs[NEXP] + j] = j & (T_TOK - 1);
    }
}

// out[t] = w0*H2[r0] + w1*H2[r1] + H2[s0] + H2[s1]  (pure write)
__global__ void combine_kernel(const uint16_t* __restrict__ H2, const int* __restrict__ row_of,
                               const float* __restrict__ wgt, const int* __restrict__ offs,
                               float* __restrict__ out) {
    int t = blockIdx.x;
    int c = threadIdx.x * 8;   // 128 threads * 8 cols
    int r0 = row_of[t * 2], r1 = row_of[t * 2 + 1];
    int s0 = offs[NEXP] + t, s1 = s0 + T_TOK;
    float w0 = wgt[t * 2], w1 = wgt[t * 2 + 1];
    uint4 a = *(const uint4*)(H2 + (size_t)r0 * DIMD + c);
    uint4 b = *(const uint4*)(H2 + (size_t)r1 * DIMD + c);
    uint4 u = *(const uint4*)(H2 + (size_t)s0 * DIMD + c);
    uint4 v = *(const uint4*)(H2 + (size_t)s1 * DIMD + c);
    float4 o0, o1;
    o0.x = w0 * bf2f(a.x & 0xffffu) + w1 * bf2f(b.x & 0xffffu) + bf2f(u.x & 0xffffu) + bf2f(v.x & 0xffffu);
    o0.y = w0 * bf2f(a.x >> 16)     + w1 * bf2f(b.x >> 16)     + bf2f(u.x >> 16)     + bf2f(v.x >> 16);
    o0.z = w0 * bf2f(a.y & 0xffffu) + w1 * bf2f(b.y & 0xffffu) + bf2f(u.y & 0xffffu) + bf2f(v.y & 0xffffu);
    o0.w = w0 * bf2f(a.y >> 16)     + w1 * bf2f(b.y >> 16)     + bf2f(u.y >> 16)     + bf2f(v.y >> 16);
    o1.x = w0 * bf2f(a.z & 0xffffu) + w1 * bf2f(b.z & 0xffffu) + bf2f(u.z & 0xffffu) + bf2f(v.z & 0xffffu);
    o1.y = w0 * bf2f(a.z >> 16)     + w1 * bf2f(b.z >> 16)     + bf2f(u.z >> 16)     + bf2f(v.z >> 16);
    o1.z = w0 * bf2f(a.w & 0xffffu) + w1 * bf2f(b.w & 0xffffu) + bf2f(u.w & 0xffffu) + bf2f(v.w & 0xffffu);
    o1.w = w0 * bf2f(a.w >> 16)     + w1 * bf2f(b.w >> 16)     + bf2f(u.w >> 16)     + bf2f(v.w >> 16);
    float* o = out + (size_t)t * DIMD + c;
    *(float4*)o = o0;
    *(float4*)(o + 4) = o1;
}

// ------------- gemm13: 256x256 tile, BK=64, 4-phase counted-vmcnt (r9, frozen) -------------
__global__ __launch_bounds__(512, 2)
void gemm13_8p(const uint16_t* __restrict__ A, const int* __restrict__ tok,
               const uint16_t* __restrict__ W, uint16_t* __restrict__ H,
               const int* __restrict__ offs) {
    constexpr int K = DIMD;       // 1024
    constexpr int NT = K / 64;    // 16 K-tiles
    __shared__ __align__(16) char lds[131072];

    int row0 = blockIdx.y * 256;
    int rsh = row0 - offs[NEXP];
    int e;
    if (rsh >= 0) {
        if (rsh >= 2 * T_TOK) return;
        e = NEXP + (rsh >> 12);
    } else {
        e = 0;
        while (row0 >= offs[e + 1]) ++e;
    }
    const uint16_t* wp = W + (size_t)e * (4096ull * 1024ull);
    int col0 = blockIdx.x * 256;

    int tid = threadIdx.x, lane = tid & 63, wid = tid >> 6;
    int wm = wid >> 2, wn = wid & 3;

    int sslot = (lane & 3) ^ ((tid >> 3) & 3);
    uint32_t aoff[2], boff[2];
    #pragma unroll
    for (int i = 0; i < 2; ++i) {
        int r = i * 128 + (tid >> 2);
        int garow = tok[row0 + r];
        aoff[i] = (uint32_t)garow * K + sslot * 8;
        boff[i] = (uint32_t)(col0 + r) * K + sslot * 8;
    }
    int ldsw = wid * 1024;

    int rslot = (((lane >> 4) ^ ((lane >> 1) & 3)) << 4);
    int aro = (wm * 128 + (lane & 15)) * 64 + rslot;
    int bro = (wn * 64 + (lane & 15)) * 64 + rslot;

    #define STAGE_A(buf, kt, ks) { \
        gload16(A + aoff[0] + (kt) + (ks) * 32, (buf) + (ks) * 16384 + ldsw); \
        gload16(A + aoff[1] + (kt) + (ks) * 32, (buf) + (ks) * 16384 + 8192 + ldsw); }
    #define STAGE_B(buf, kt, ks) { \
        gload16(wp + boff[0] + (kt) + (ks) * 32, (buf) + 32768 + (ks) * 16384 + ldsw); \
        gload16(wp + boff[1] + (kt) + (ks) * 32, (buf) + 32768 + (ks) * 16384 + 8192 + ldsw); }

    STAGE_A(lds, 0, 0); STAGE_B(lds, 0, 0);
    STAGE_A(lds, 0, 1); STAGE_B(lds, 0, 1);
    WAIT_VM4();
    BAR();

    f32x4 acc[8][4] = {};

    for (int t = 0; t < NT; ++t) {
        char* cur = lds + (t & 1) * 65536;
        char* nxt = lds + ((t + 1) & 1) * 65536;
        int kt1 = (t + 1) * 64;
        bool pre = (t + 1 < NT);
        s16x8 av[4], bv[4], av2[4];

        // ---- ph1: ks0, frag-rows 0-3 ; stage Aks0(t+1)
        #pragma unroll
        for (int f = 0; f < 4; ++f) av[f] = *(const s16x8*)(cur + aro + f * 1024);
        #pragma unroll
        for (int f = 0; f < 4; ++f) bv[f] = *(const s16x8*)(cur + 32768 + bro + f * 1024);
        if (pre) STAGE_A(nxt, kt1, 0);
        BAR(); WAIT_LGKM0();
        __builtin_amdgcn_s_setprio(1);
        #pragma unroll
        for (int j = 0; j < 4; ++j)
            #pragma unroll
            for (int i = 0; i < 4; ++i)
                acc[i][j] = __builtin_amdgcn_mfma_f32_16x16x32_bf16(av[i], bv[j], acc[i][j], 0, 0, 0);
        __builtin_amdgcn_s_setprio(0);
        BAR();

        // ---- ph2: ks0, frag-rows 4-7 ; stage Bks0(t+1)
        #pragma unroll
        for (int f = 0; f < 4; ++f) av2[f] = *(const s16x8*)(cur + aro + (f + 4) * 1024);
        if (pre) STAGE_B(nxt, kt1, 0);
        BAR(); WAIT_LGKM0();
        __builtin_amdgcn_s_setprio(1);
        #pragma unroll
        for (int j = 0; j < 4; ++j)
            #pragma unroll
            for (int i = 0; i < 4; ++i)
                acc[i + 4][j] = __builtin_amdgcn_mfma_f32_16x16x32_bf16(av2[i], bv[j], acc[i + 4][j], 0, 0, 0);
        __builtin_amdgcn_s_setprio(0);
        if (pre) { WAIT_VM4(); } else { WAIT_VM0(); }
        BAR();

        // ---- ph3: ks1, frag-rows 0-3 ; stage Aks1(t+1)
        #pragma unroll
        for (int f = 0; f < 4; ++f) av[f] = *(const s16x8*)(cur + 16384 + aro + f * 1024);
        #pragma unroll
        for (int f = 0; f < 4; ++f) bv[f] = *(const s16x8*)(cur + 32768 + 16384 + bro + f * 1024);
        if (pre) STAGE_A(nxt, kt1, 1);
        BAR(); WAIT_LGKM0();
        __builtin_amdgcn_s_setprio(1);
        #pragma unroll
        for (int j = 0; j < 4; ++j)
            #pragma unroll
            for (int i = 0; i < 4; ++i)
                acc[i][j] = __builtin_amdgcn_mfma_f32_16x16x32_bf16(av[i], bv[j], acc[i][j], 0, 0, 0);
        __builtin_amdgcn_s_setprio(0);
        BAR();

        // ---- ph4: ks1, frag-rows 4-7 ; stage Bks1(t+1)
        #pragma unroll
        for (int f = 0; f < 4; ++f) av2[f] = *(const s16x8*)(cur + 16384 + aro + (f + 4) * 1024);
        if (pre) STAGE_B(nxt, kt1, 1);
        BAR(); WAIT_LGKM0();
        __builtin_amdgcn_s_setprio(1);
        #pragma unroll
        for (int j = 0; j < 4; ++j)
            #pragma unroll
            for (int i = 0; i < 4; ++i)
                acc[i + 4][j] = __builtin_amdgcn_mfma_f32_16x16x32_bf16(av2[i], bv[j], acc[i + 4][j], 0, 0, 0);
        __builtin_amdgcn_s_setprio(0);
        if (pre) WAIT_VM4();
        BAR();
    }
    #undef STAGE_A
    #undef STAGE_B

    // ---- epilogue: silu(w1-frag)*w3-frag; cols interleaved at 16 granule
    #pragma unroll
    for (int i = 0; i < 8; ++i) {
        int row = row0 + wm * 128 + i * 16 + ((lane >> 4) << 2);
        #pragma unroll
        for (int m = 0; m < 2; ++m) {
            int hc = ((col0 + wn * 64) >> 1) + m * 16 + (lane & 15);
            #pragma unroll
            for (int rg = 0; rg < 4; ++rg) {
                float a1 = acc[i][2 * m][rg];
                float a3 = acc[i][2 * m + 1][rg];
                float hv = (a1 / (1.f + __expf(-a1))) * a3;
                H[(size_t)(row + rg) * HIDN + hc] = f2bf(hv);
            }
        }
    }
}

// ------------- gemm2: 128x128 tile, BK=64, 2-phase counted-vmcnt pipeline -------------
// 256 thr = 4 waves (2x2), per-wave 64x64 = acc[4][4]. LDS 2 bufs x 32KB -> 2 blocks/CU
// (cross-block overlap hides prefetch shallowness). Buf = {A-ks0 8K, A-ks1 8K, B-ks0 8K,
// B-ks1 8K}; each ks-block [128 rows][64B], slot = chunk ^ ((row>>1)&3) (r9-verified
// conflict-free). Ledger: entry = ks1(t) 4 outstanding; ph1 stages ks0(t+1), waits
// vmcnt(4) (=ks1(t)); ph2 stages ks1(t+1), waits vmcnt(4) (=ks0(t+1)). Never drains.
__global__ __launch_bounds__(256, 2)
void gemm2_2p(const uint16_t* __restrict__ Hg,
              const uint16_t* __restrict__ W2, uint16_t* __restrict__ H2,
              const int* __restrict__ offs) {
    constexpr int K = HIDN;       // 2048
    constexpr int NT = K / 64;    // 32 K-tiles
    __shared__ __align__(16) char lds[65536];

    int row0 = blockIdx.y * 128;
    int rsh = row0 - offs[NEXP];
    int e;
    if (rsh >= 0) {
        if (rsh >= 2 * T_TOK) return;
        e = NEXP + (rsh >> 12);
    } else {
        e = 0;
        while (row0 >= offs[e + 1]) ++e;
    }
    const uint16_t* wp = W2 + (size_t)e * DIMD * HIDN;
    int col0 = blockIdx.x * 128;

    int tid = threadIdx.x, lane = tid & 63, wid = tid >> 6;
    int wm = wid >> 1, wn = wid & 1;

    // staging: issue p covers rows p*64 + (tid>>2), chunk slot tid&3 holds
    // source chunk (tid&3) ^ ((tid>>3)&3)   [= slot ^ ((row>>1)&3)]
    int chunk = (tid & 3) ^ ((tid >> 3) & 3);
    uint32_t aoff[2], boff[2];
    #pragma unroll
    for (int p = 0; p < 2; ++p) {
        int r = p * 64 + (tid >> 2);
        aoff[p] = (uint32_t)(row0 + r) * K + chunk * 8;
        boff[p] = (uint32_t)(col0 + r) * K + chunk * 8;
    }
    int ldsw = wid * 1024;   // wave-uniform base within each 4KB issue region

    // read side: slot = (lane>>4) ^ ((lane>>1)&3), frag-row-independent
    int rslot = (((lane >> 4) ^ ((lane >> 1) & 3)) << 4);
    int aro = (wm * 64 + (lane & 15)) * 64 + rslot;            // + f*1024 + ks*8192
    int bro = (wn * 64 + (lane & 15)) * 64 + rslot + 16384;    // + f*1024 + ks*8192

    #define STG_A2(buf, kt, ks) { \
        gload16(Hg + aoff[0] + (kt) + (ks) * 32, (buf) + (ks) * 8192 + ldsw); \
        gload16(Hg + aoff[1] + (kt) + (ks) * 32, (buf) + (ks) * 8192 + 4096 + ldsw); }
    #define STG_B2(buf, kt, ks) { \
        gload16(wp + boff[0] + (kt) + (ks) * 32, (buf) + 16384 + (ks) * 8192 + ldsw); \
        gload16(wp + boff[1] + (kt) + (ks) * 32, (buf) + 16384 + (ks) * 8192 + 4096 + ldsw); }

    // prologue: tile 0 (ks0 first, then ks1)
    STG_A2(lds, 0, 0); STG_B2(lds, 0, 0);
    STG_A2(lds, 0, 1); STG_B2(lds, 0, 1);
    WAIT_VM4();          // ks0 landed; ks1 (4 loads) in flight
    BAR();

    f32x4 acc[4][4] = {};

    for (int t = 0; t < NT; ++t) {
        char* cur = lds + (t & 1) * 32768;
        char* nxt = lds + ((t + 1) & 1) * 32768;
        int kt1 = (t + 1) * 64;
        bool pre = (t + 1 < NT);
        s16x8 av[4], bv[4];

        // ---- ph1: ks0 (16 MFMA) ; stage ks0(t+1)
        #pragma unroll
        for (int f = 0; f < 4; ++f) av[f] = *(const s16x8*)(cur + aro + f * 1024);
        #pragma unroll
        for (int f = 0; f < 4; ++f) bv[f] = *(const s16x8*)(cur + bro + f * 1024);
        if (pre) { STG_A2(nxt, kt1, 0); STG_B2(nxt, kt1, 0); }
        BAR(); WAIT_LGKM0();
        __builtin_amdgcn_s_setprio(1);
        #pragma unroll
        for (int j = 0; j < 4; ++j)
            #pragma unroll
            for (int i = 0; i < 4; ++i)
                acc[i][j] = __builtin_amdgcn_mfma_f32_16x16x32_bf16(av[i], bv[j], acc[i][j], 0, 0, 0);
        __builtin_amdgcn_s_setprio(0);
        if (pre) { WAIT_VM4(); } else { WAIT_VM0(); }   // ks1(t) landed
        BAR();

        // ---- ph2: ks1 (16 MFMA) ; stage ks1(t+1)
        #pragma unroll
        for (int f = 0; f < 4; ++f) av[f] = *(const s16x8*)(cur + 8192 + aro + f * 1024);
        #pragma unroll
        for (int f = 0; f < 4; ++f) bv[f] = *(const s16x8*)(cur + 8192 + bro + f * 1024);
        if (pre) { STG_A2(nxt, kt1, 1); STG_B2(nxt, kt1, 1); }
        BAR(); WAIT_LGKM0();
        __builtin_amdgcn_s_setprio(1);
        #pragma unroll
        for (int j = 0; j < 4; ++j)
            #pragma unroll
            for (int i = 0; i < 4; ++i)
                acc[i][j] = __builtin_amdgcn_mfma_f32_16x16x32_bf16(av[i], bv[j], acc[i][j], 0, 0, 0);
        __builtin_amdgcn_s_setprio(0);
        if (pre) WAIT_VM4();                            // ks0(t+1) landed
        BAR();
    }
    #undef STG_A2
    #undef STG_B2

    #pragma unroll
    for (int i = 0; i < 4; ++i) {
        #pragma unroll
        for (int j = 0; j < 4; ++j) {
            #pragma unroll
            for (int rg = 0; rg < 4; ++rg) {
                int row = row0 + wm * 64 + i * 16 + ((lane >> 4) << 2) + rg;
                int col = col0 + wn * 64 + j * 16 + (lane & 15);
                H2[(size_t)row * DIMD + col] = f2bf(acc[i][j][rg]);
            }
        }
    }
}

// ---------------- launch ----------------

extern "C" void kernel_launch(void* const* d_in, const int* in_sizes, int n_in,
                              void* d_out, int out_size, void* d_ws, size_t ws_size,
                              hipStream_t stream) {
    const float* x   = (const float*)d_in[0];
    const float* rw  = (const float*)d_in[1];
    const float* eb  = (const float*)d_in[2];
    const float* w1  = (const float*)d_in[3];
    const float* w3  = (const float*)d_in[4];
    const float* w2  = (const float*)d_in[5];
    const float* sw1 = (const float*)d_in[6];
    const float* sw3 = (const float*)d_in[7];
    const float* sw2 = (const float*)d_in[8];
    float* out = (float*)d_out;

    const size_t EW = (size_t)NEXP * HIDN * DIMD;
    const size_t SW = (size_t)2 * HIDN * DIMD;

    char* ws = (char*)d_ws;
    size_t off = 0;
    auto alloc = [&](size_t b) { char* p = ws + off; off = (off + b + 255) & ~(size_t)255; return p; };
    uint16_t* xb    = (uint16_t*)alloc((size_t)T_TOK * DIMD * 2);
    uint16_t* Hg    = (uint16_t*)alloc((size_t)RROWS * HIDN * 2);
    uint16_t* H2    = (uint16_t*)alloc((size_t)RROWS * DIMD * 2);
    uint16_t* w13   = (uint16_t*)alloc((size_t)10 * 4096 * 1024 * 2);  // interleaved, 10 experts
    uint16_t* w2all = (uint16_t*)alloc((EW + SW) * 2);
    int*   sel    = (int*)  alloc(T_TOK * 2 * 4);
    float* wgt    = (float*)alloc(T_TOK * 2 * 4);
    int*   row_of = (int*)  alloc(T_TOK * 2 * 4);
    int*   tok    = (int*)  alloc(RROWS * 4);
    int*   cnt    = (int*)  alloc(64);
    int*   fill   = (int*)  alloc(64);
    int*   offs   = (int*)  alloc(64);

    hipMemsetAsync(cnt, 0, 64, stream);
    hipMemsetAsync(fill, 0, 64, stream);
    hipMemsetAsync(tok, 0, RROWS * 4, stream);   // pad rows -> token 0 (harmless)

    CvtArgs ca;
    ca.s[0] = w1;  ca.d[0] = w13;                           ca.nq[0] = (int)(EW / 4); ca.mode[0] = 1;
    ca.s[1] = sw1; ca.d[1] = w13 + (size_t)8 * 4096 * 1024; ca.nq[1] = (int)(SW / 4); ca.mode[1] = 1;
    ca.s[2] = w3;  ca.d[2] = w13;                           ca.nq[2] = (int)(EW / 4); ca.mode[2] = 2;
    ca.s[3] = sw3; ca.d[3] = w13 + (size_t)8 * 4096 * 1024; ca.nq[3] = (int)(SW / 4); ca.mode[3] = 2;
    ca.s[4] = w2;  ca.d[4] = w2all;                         ca.nq[4] = (int)(EW / 4); ca.mode[4] = 0;
    ca.s[5] = sw2; ca.d[5] = w2all + EW;                    ca.nq[5] = (int)(SW / 4); ca.mode[5] = 0;
    ca.s[6] = x;   ca.d[6] = xb;                            ca.nq[6] = T_TOK * DIMD / 4; ca.mode[6] = 0;
    cvt_all_kernel<<<2048, 256, 0, stream>>>(ca);

    router_kernel<<<128, 256, 0, stream>>>(x, rw, eb, sel, wgt, cnt);
    offs_kernel<<<1, 1, 0, stream>>>(cnt, offs);
    assign_kernel<<<64, 256, 0, stream>>>(sel, offs, fill, row_of, tok);

    gemm13_8p<<<dim3(16, RROWS / 256), 512, 0, stream>>>(xb, tok, w13, Hg, offs);
    gemm2_2p<<<dim3(DIMD / 128, RROWS / 128), 256, 0, stream>>>(Hg, w2all, H2, offs);

    combine_kernel<<<T_TOK, 128, 0, stream>>>(H2, row_of, wgt, offs, out);
}